// Round 1
// baseline (286.442 us; speedup 1.0000x reference)
//
#include <hip/hip_runtime.h>

// LSTM: B=16384 independent sequences, T=512, I=4, H=4, then FC 4->1.
// Round 3: occupancy attack. Previous kernel used 4 lanes/seq -> 65536
// threads = 1024 waves = exactly 1 wave/SIMD. Waves issue IN ORDER, so the
// ~300-cycle/step serial recurrence chain (h -> fma chain -> exp2/rcp ->
// c -> tanh -> h) stalls the SIMD with nothing to fill it (VALUBusy 40%).
// Now each sequence is split across 8 lanes: lanes j=0..3 own gate pair
// (i_j,f_j), lanes 4..7 own (g_j,o_j). 131072 threads = 2048 waves =
// 2 waves/SIMD; per-wave issue/step halves and the second wave's ready
// instructions fill the first wave's transcendental dep stalls.
// Gate pairs are exchanged across the xor-4 lane boundary with ds_swizzle
// (0x101F); both half-quads redundantly compute c/h so the h-broadcast
// stays 3 quad-perm DPPs (h_j identical on lanes j and j+4).

#define CH 4  // time-chunk for double-buffered X prefetch

typedef float v2f __attribute__((ext_vector_type(2)));

__device__ __forceinline__ v2f pk_fma(v2f a, v2f b, v2f c) {
    return __builtin_elementwise_fma(a, b, c);
}

// DPP quad_perm lane xor within aligned quads: xor1=0xB1, xor2=0x4E, xor3=0x1B
template <int CTRL>
__device__ __forceinline__ float quad_xor(float v) {
    int i = __float_as_int(v);
    int r = __builtin_amdgcn_mov_dpp(i, CTRL, 0xF, 0xF, true);
    return __int_as_float(r);
}

// ds_swizzle bitmode: and=0x1F, or=0, xor=4 -> lane ^ 4 (within 32-lane group)
__device__ __forceinline__ float swz_xor4(float v) {
    int r = __builtin_amdgcn_ds_swizzle(__float_as_int(v), 0x101F);
    return __int_as_float(r);
}

__global__ __launch_bounds__(256) void lstm_h4_kernel(
    const float* __restrict__ X,
    const float* __restrict__ W_ih,
    const float* __restrict__ W_hh,
    const float* __restrict__ b_ih,
    const float* __restrict__ b_hh,
    const float* __restrict__ W_fc,
    const float* __restrict__ b_fc,
    float* __restrict__ out,
    int B, int T)
{
    int gid = blockIdx.x * blockDim.x + threadIdx.x;
    int b  = gid >> 3;        // sequence index (8 lanes per sequence)
    int j  = gid & 3;         // hidden unit index
    int ps = (gid >> 2) & 1;  // 0: this lane owns (i_j,f_j); 1: (g_j,o_j)
    if (b >= B) return;

    // Gate order (PyTorch rows): 0-3=i, 4-7=f, 8-11=g, 12-15=o.
    // ps=0 -> rows (j, 4+j) = (i_j, f_j); ps=1 -> rows (8+j, 12+j) = (g_j, o_j).
    int rA = ps * 8 + j;
    int rB = rA + 4;

    v2f wih[4], whh[4], bias;
#pragma unroll
    for (int k = 0; k < 4; ++k) {
        wih[k] = (v2f){W_ih[rA * 4 + k], W_ih[rB * 4 + k]};
        int kc = j ^ k;   // h slot k carries h_{j^k} (quad xor broadcast order)
        whh[k] = (v2f){W_hh[rA * 4 + kc], W_hh[rB * 4 + kc]};
    }
    bias = (v2f){b_ih[rA] + b_hh[rA], b_ih[rB] + b_hh[rB]};

    // Nonlinearity constants, packed per pair:
    //   y = s * rcp(1 + exp2(m*x)) + t
    //   sigmoid: m=-1.4427, s=1, t=0;  tanh: m=-2.8854, s=2, t=-1
    const v2f mm = ps ? (v2f){-2.88539008f, -1.44269504f}   // (tanh g, sig o)
                      : (v2f){-1.44269504f, -1.44269504f};  // (sig i, sig f)
    const v2f ss = ps ? (v2f){2.0f, 1.0f} : (v2f){1.0f, 1.0f};
    const v2f tt = ps ? (v2f){-1.0f, 0.0f} : (v2f){0.0f, 0.0f};

    const float4* __restrict__ xp = (const float4*)X + (size_t)b * T;

    float h = 0.0f, c = 0.0f;

    float4 cur[CH], nxt[CH];
#pragma unroll
    for (int i = 0; i < CH; ++i) cur[i] = xp[i];

    for (int tc = 0; tc < T; tc += CH) {
        if (tc + CH < T) {
#pragma unroll
            for (int i = 0; i < CH; ++i) nxt[i] = xp[tc + CH + i];
        }
#pragma unroll
        for (int i = 0; i < CH; ++i) {
            float4 x = cur[i];
            // ---- x path: independent of recurrence (scheduler slack) ----
            v2f p = bias;
            p = pk_fma(wih[0], (v2f){x.x, x.x}, p);
            p = pk_fma(wih[1], (v2f){x.y, x.y}, p);
            p = pk_fma(wih[2], (v2f){x.z, x.z}, p);
            p = pk_fma(wih[3], (v2f){x.w, x.w}, p);

            // ---- recurrence path ----
            float h1 = quad_xor<0xB1>(h);
            float h2 = quad_xor<0x4E>(h);
            float h3 = quad_xor<0x1B>(h);
            p = pk_fma(whh[0], (v2f){h,  h},  p);
            p = pk_fma(whh[1], (v2f){h1, h1}, p);
            p = pk_fma(whh[2], (v2f){h2, h2}, p);
            p = pk_fma(whh[3], (v2f){h3, h3}, p);

            // ---- own pair nonlinearity (2 exp2 + 2 rcp per lane) ----
            v2f a = p * mm;
            v2f e = (v2f){__builtin_amdgcn_exp2f(a.x),
                          __builtin_amdgcn_exp2f(a.y)};
            v2f d = e + (v2f){1.0f, 1.0f};
            v2f r = (v2f){__builtin_amdgcn_rcpf(d.x),
                          __builtin_amdgcn_rcpf(d.y)};
            v2f own = pk_fma(ss, r, tt);   // ps=0: (i,f)  ps=1: (g,o)

            // ---- exchange pairs across the xor-4 boundary ----
            v2f oth = (v2f){swz_xor4(own.x), swz_xor4(own.y)};

            float iv = ps ? oth.x : own.x;
            float fv = ps ? oth.y : own.y;
            float gv = ps ? own.x : oth.x;
            float ov = ps ? own.y : oth.y;

            // ---- c/h computed redundantly on both half-quads ----
            c = fmaf(fv, c, iv * gv);
            float ec = __builtin_amdgcn_exp2f(-2.88539008f * c);
            float th = fmaf(2.0f, __builtin_amdgcn_rcpf(1.0f + ec), -1.0f);
            h = ov * th;
        }
        if (tc + CH < T) {
#pragma unroll
            for (int i = 0; i < CH; ++i) cur[i] = nxt[i];
        }
    }

    // out[b] = sum_j h_j * W_fc[j] + b_fc  (reduce across the quad;
    // both half-quads hold identical h, lane 0 of the octet writes)
    float partial = h * W_fc[j];
    partial += quad_xor<0xB1>(partial);
    partial += quad_xor<0x4E>(partial);
    if ((gid & 7) == 0) out[b] = partial + b_fc[0];
}

extern "C" void kernel_launch(void* const* d_in, const int* in_sizes, int n_in,
                              void* d_out, int out_size, void* d_ws, size_t ws_size,
                              hipStream_t stream) {
    const float* X    = (const float*)d_in[0];
    const float* W_ih = (const float*)d_in[1];
    const float* W_hh = (const float*)d_in[2];
    const float* b_ih = (const float*)d_in[3];
    const float* b_hh = (const float*)d_in[4];
    const float* W_fc = (const float*)d_in[5];
    const float* b_fc = (const float*)d_in[6];
    float* out = (float*)d_out;

    int B = out_size;                       // 16384
    int T = in_sizes[0] / (B * 4);          // 512 (I=4)

    int threads = B * 8;                    // 8 lanes per sequence
    dim3 block(256);
    dim3 grid((threads + 255) / 256);
    lstm_h4_kernel<<<grid, block, 0, stream>>>(X, W_ih, W_hh, b_ih, b_hh,
                                               W_fc, b_fc, out, B, T);
}

// Round 2
// 252.301 us; speedup vs baseline: 1.1353x; 1.1353x over previous
//
#include <hip/hip_runtime.h>

// LSTM: B=16384 independent sequences, T=512, I=4, H=4, then FC 4->1.
// Round 4: chain surgery. R3 proved we are dep-chain-latency bound (2x
// occupancy, same VALUBusy, worse time: waves overlap fully; per-SIMD
// throughput = 64 lanes-chains / chain-length). So: revert to 4 lanes/seq
// (1 wave/SIMD) and shorten the per-step critical cycle
//   h -> U*h -> sigmoid -> c' -> tanh -> h'
// by: (1) folding the -1.4427/-2.8854 exp2 pre-scales into W_ih/W_hh/bias
// at load time (no on-chain mul before exp2); (2) carrying the cell in
// scaled form s = -2.8854*c so tanh(c) = 2*rcp(1+exp2(s))-1 needs no
// on-chain scale; (3) depth-3 tree for the h-dot; (4) h = fma(2o, r_c, -o)
// with 2o precomputed off-chain. On-chain ops: 16 -> 11 (4 trans remain).

#define CH 8  // time-chunk for double-buffered X prefetch

typedef float v2f __attribute__((ext_vector_type(2)));

__device__ __forceinline__ v2f pk_fma(v2f a, v2f b, v2f c) {
    return __builtin_elementwise_fma(a, b, c);
}

// DPP quad_perm lane xor within aligned quads: xor1=0xB1, xor2=0x4E, xor3=0x1B
template <int CTRL>
__device__ __forceinline__ float quad_xor(float v) {
    int i = __float_as_int(v);
    int r = __builtin_amdgcn_mov_dpp(i, CTRL, 0xF, 0xF, true);
    return __int_as_float(r);
}

__global__ __launch_bounds__(256) void lstm_h4_kernel(
    const float* __restrict__ X,
    const float* __restrict__ W_ih,
    const float* __restrict__ W_hh,
    const float* __restrict__ b_ih,
    const float* __restrict__ b_hh,
    const float* __restrict__ W_fc,
    const float* __restrict__ b_fc,
    float* __restrict__ out,
    int B, int T)
{
    int gid = blockIdx.x * blockDim.x + threadIdx.x;
    int b = gid >> 2;       // sequence index
    int j = gid & 3;        // hidden unit index
    if (b >= B) return;

    // Gate order (PyTorch rows): 0-3=i, 4-7=f, 8-11=g, 12-15=o.
    // Pair 0 = (f_j, i_j) rows (4+j, j)   <- f first: it sits on the c-spine
    // Pair 1 = (g_j, o_j) rows (8+j, 12+j)
    // exp2 pre-scales folded into weights: sigmoid rows * -1.4427,
    // tanh (g) rows * -2.8854. whh_*[k] multiplies h from lane j^k.
    const float MS = -1.44269504f;   // sigmoid: exp2(MS*a)
    const float MT = -2.88539008f;   // tanh:    exp2(MT*a)

    v2f wih0[4], wih1[4], whh0[4], whh1[4], bias0, bias1;
    {
        int rI = 0 * 4 + j, rF = 1 * 4 + j, rG = 2 * 4 + j, rO = 3 * 4 + j;
#pragma unroll
        for (int k = 0; k < 4; ++k) {
            wih0[k] = (v2f){MS * W_ih[rF * 4 + k], MS * W_ih[rI * 4 + k]};
            wih1[k] = (v2f){MT * W_ih[rG * 4 + k], MS * W_ih[rO * 4 + k]};
            int kc = j ^ k;
            whh0[k] = (v2f){MS * W_hh[rF * 4 + kc], MS * W_hh[rI * 4 + kc]};
            whh1[k] = (v2f){MT * W_hh[rG * 4 + kc], MS * W_hh[rO * 4 + kc]};
        }
        bias0 = (v2f){MS * (b_ih[rF] + b_hh[rF]), MS * (b_ih[rI] + b_hh[rI])};
        bias1 = (v2f){MT * (b_ih[rG] + b_hh[rG]), MS * (b_ih[rO] + b_hh[rO])};
    }

    const float4* __restrict__ xp = (const float4*)X + (size_t)b * T;

    float h = 0.0f;
    float s = 0.0f;   // scaled cell state: s = -2.8854 * c

    float4 cur[CH], nxt[CH];
#pragma unroll
    for (int i = 0; i < CH; ++i) cur[i] = xp[i];

    for (int tc = 0; tc < T; tc += CH) {
        if (tc + CH < T) {
#pragma unroll
            for (int i = 0; i < CH; ++i) nxt[i] = xp[tc + CH + i];
        }
#pragma unroll
        for (int i = 0; i < CH; ++i) {
            float4 x = cur[i];
            // ---- x path: independent of recurrence (scheduler slack) ----
            v2f px0 = bias0, px1 = bias1;
            px0 = pk_fma(wih0[0], (v2f){x.x, x.x}, px0);
            px1 = pk_fma(wih1[0], (v2f){x.x, x.x}, px1);
            px0 = pk_fma(wih0[1], (v2f){x.y, x.y}, px0);
            px1 = pk_fma(wih1[1], (v2f){x.y, x.y}, px1);
            px0 = pk_fma(wih0[2], (v2f){x.z, x.z}, px0);
            px1 = pk_fma(wih1[2], (v2f){x.z, x.z}, px1);
            px0 = pk_fma(wih0[3], (v2f){x.w, x.w}, px0);
            px1 = pk_fma(wih1[3], (v2f){x.w, x.w}, px1);

            // ---- recurrence path: depth-3 tree dot ----
            float h1 = quad_xor<0xB1>(h);
            float h2 = quad_xor<0x4E>(h);
            float h3 = quad_xor<0x1B>(h);
            v2f hb0 = (v2f){h,  h};
            v2f hb1 = (v2f){h1, h1};
            v2f hb2 = (v2f){h2, h2};
            v2f hb3 = (v2f){h3, h3};
            v2f A0 = pk_fma(whh0[0], hb0, px0);
            v2f A1 = pk_fma(whh1[0], hb0, px1);
            A0 = pk_fma(whh0[1], hb1, A0);
            A1 = pk_fma(whh1[1], hb1, A1);
            v2f B0 = whh0[2] * hb2;
            v2f B1 = whh1[2] * hb2;
            B0 = pk_fma(whh0[3], hb3, B0);
            B1 = pk_fma(whh1[3], hb3, B1);
            v2f a0 = A0 + B0;   // (af', ai')  pre-scaled
            v2f a1 = A1 + B1;   // (ag', ao')  pre-scaled

            // ---- nonlinearities: r = rcp(1 + exp2(a')) ----
            float ef = __builtin_amdgcn_exp2f(a0.x);   // f first: c-spine
            float eg = __builtin_amdgcn_exp2f(a1.x);
            float ei = __builtin_amdgcn_exp2f(a0.y);
            float eo = __builtin_amdgcn_exp2f(a1.y);
            float rf = __builtin_amdgcn_rcpf(1.0f + ef);   // = sigmoid(af)
            float rg = __builtin_amdgcn_rcpf(1.0f + eg);   // tanh(ag)=2rg-1
            float ri = __builtin_amdgcn_rcpf(1.0f + ei);   // = sigmoid(ai)
            float ro = __builtin_amdgcn_rcpf(1.0f + eo);   // = sigmoid(ao)

            // s' = f*s + (-2.8854)*i*g ;  -2.8854*g = -5.7708*rg + 2.8854
            float gsc = fmaf(-5.77078016f, rg, 2.88539008f);
            float igs = ri * gsc;
            s = fmaf(rf, s, igs);

            // h' = o * tanh(c') = o*(2*rcp(1+exp2(s)) - 1) = fma(2o, rc, -o)
            float ec = __builtin_amdgcn_exp2f(s);
            float rc = __builtin_amdgcn_rcpf(1.0f + ec);
            float o2 = ro + ro;                 // off-chain
            h = fmaf(o2, rc, -ro);
        }
#pragma unroll
        for (int i = 0; i < CH; ++i) cur[i] = nxt[i];
    }

    // out[b] = sum_j h_j * W_fc[j] + b_fc  (reduce across the quad)
    float partial = h * W_fc[j];
    partial += quad_xor<0xB1>(partial);
    partial += quad_xor<0x4E>(partial);
    if (j == 0) out[b] = partial + b_fc[0];
}

extern "C" void kernel_launch(void* const* d_in, const int* in_sizes, int n_in,
                              void* d_out, int out_size, void* d_ws, size_t ws_size,
                              hipStream_t stream) {
    const float* X    = (const float*)d_in[0];
    const float* W_ih = (const float*)d_in[1];
    const float* W_hh = (const float*)d_in[2];
    const float* b_ih = (const float*)d_in[3];
    const float* b_hh = (const float*)d_in[4];
    const float* W_fc = (const float*)d_in[5];
    const float* b_fc = (const float*)d_in[6];
    float* out = (float*)d_out;

    int B = out_size;                       // 16384
    int T = in_sizes[0] / (B * 4);          // 512 (I=4)

    int threads = B * 4;
    dim3 block(256);
    dim3 grid((threads + 255) / 256);
    lstm_h4_kernel<<<grid, block, 0, stream>>>(X, W_ih, W_hh, b_ih, b_hh,
                                               W_fc, b_fc, out, B, T);
}

// Round 3
// 246.685 us; speedup vs baseline: 1.1612x; 1.0228x over previous
//
#include <hip/hip_runtime.h>

// LSTM: B=16384 independent sequences, T=512, I=4, H=4, then FC 4->1.
// Round 5: transcendental-count attack. R3 (2x waves: no gain) + R4 (ALU
// chain surgery: no gain) prove per-step time is dominated by the 10
// quarter-rate transcendentals (v_exp_f32/v_rcp_f32, ~16 cyc issue each +
// latency exposure under in-order single-wave issue): 10x16=160 of the 208
// busy cycles/step, plus ~300 stall cycles of exposed trans latency.
// Fix: merge reciprocals algebraically. Scaled cell s = -2.885*c:
//   s' = (s*pi*pg + pf*MT*(1-eg)) / (pf*pi*pg)      <- ONE rcp (was 3)
//   h' = o*tanh(c') = (1-es) / (po*(1+es)),  es=exp2(s')  <- ONE rcp (was 2)
// where px = 1+exp2(pre-scaled preactivation). 5 exp2 + 2 rcp = 7 trans
// (was 10). exp2 pre-scales folded into weights (R4). Saturation is
// graceful: es->0 flushes (h -> +o); upper side guarded by fminf(s,88)
// (h -> -o exactly as tanh saturates).

#define CH 8  // time-chunk for double-buffered X prefetch

typedef float v2f __attribute__((ext_vector_type(2)));

__device__ __forceinline__ v2f pk_fma(v2f a, v2f b, v2f c) {
    return __builtin_elementwise_fma(a, b, c);
}

// DPP quad_perm lane xor within aligned quads: xor1=0xB1, xor2=0x4E, xor3=0x1B
template <int CTRL>
__device__ __forceinline__ float quad_xor(float v) {
    int i = __float_as_int(v);
    int r = __builtin_amdgcn_mov_dpp(i, CTRL, 0xF, 0xF, true);
    return __int_as_float(r);
}

__global__ __launch_bounds__(256) void lstm_h4_kernel(
    const float* __restrict__ X,
    const float* __restrict__ W_ih,
    const float* __restrict__ W_hh,
    const float* __restrict__ b_ih,
    const float* __restrict__ b_hh,
    const float* __restrict__ W_fc,
    const float* __restrict__ b_fc,
    float* __restrict__ out,
    int B, int T)
{
    int gid = blockIdx.x * blockDim.x + threadIdx.x;
    int b = gid >> 2;       // sequence index
    int j = gid & 3;        // hidden unit index
    if (b >= B) return;

    // Gate order (PyTorch rows): 0-3=i, 4-7=f, 8-11=g, 12-15=o.
    // Pair 0 = (f_j, i_j) rows (4+j, j); pair 1 = (g_j, o_j) rows (8+j,12+j).
    // exp2 pre-scales folded: sigmoid rows * MS, tanh (g) row * MT.
    const float MS = -1.44269504f;   // -log2(e)
    const float MT = -2.88539008f;   // -2*log2(e)

    v2f wih0[4], wih1[4], whh0[4], whh1[4], bias0, bias1;
    {
        int rI = 0 * 4 + j, rF = 1 * 4 + j, rG = 2 * 4 + j, rO = 3 * 4 + j;
#pragma unroll
        for (int k = 0; k < 4; ++k) {
            wih0[k] = (v2f){MS * W_ih[rF * 4 + k], MS * W_ih[rI * 4 + k]};
            wih1[k] = (v2f){MT * W_ih[rG * 4 + k], MS * W_ih[rO * 4 + k]};
            int kc = j ^ k;
            whh0[k] = (v2f){MS * W_hh[rF * 4 + kc], MS * W_hh[rI * 4 + kc]};
            whh1[k] = (v2f){MT * W_hh[rG * 4 + kc], MS * W_hh[rO * 4 + kc]};
        }
        bias0 = (v2f){MS * (b_ih[rF] + b_hh[rF]), MS * (b_ih[rI] + b_hh[rI])};
        bias1 = (v2f){MT * (b_ih[rG] + b_hh[rG]), MS * (b_ih[rO] + b_hh[rO])};
    }

    const float4* __restrict__ xp = (const float4*)X + (size_t)b * T;

    float h = 0.0f;
    float s = 0.0f;   // scaled cell state: s = -2.8854 * c

    float4 cur[CH], nxt[CH];
#pragma unroll
    for (int i = 0; i < CH; ++i) cur[i] = xp[i];

    for (int tc = 0; tc < T; tc += CH) {
        if (tc + CH < T) {
#pragma unroll
            for (int i = 0; i < CH; ++i) nxt[i] = xp[tc + CH + i];
        }
#pragma unroll
        for (int i = 0; i < CH; ++i) {
            float4 x = cur[i];
            // ---- x path: independent of recurrence (scheduler slack) ----
            v2f p0 = bias0, p1 = bias1;
            p0 = pk_fma(wih0[0], (v2f){x.x, x.x}, p0);
            p1 = pk_fma(wih1[0], (v2f){x.x, x.x}, p1);
            p0 = pk_fma(wih0[1], (v2f){x.y, x.y}, p0);
            p1 = pk_fma(wih1[1], (v2f){x.y, x.y}, p1);
            p0 = pk_fma(wih0[2], (v2f){x.z, x.z}, p0);
            p1 = pk_fma(wih1[2], (v2f){x.z, x.z}, p1);
            p0 = pk_fma(wih0[3], (v2f){x.w, x.w}, p0);
            p1 = pk_fma(wih1[3], (v2f){x.w, x.w}, p1);

            // ---- recurrence path: chained dot (R2-style schedule) ----
            float h1 = quad_xor<0xB1>(h);
            float h2 = quad_xor<0x4E>(h);
            float h3 = quad_xor<0x1B>(h);
            p0 = pk_fma(whh0[0], (v2f){h,  h},  p0);
            p1 = pk_fma(whh1[0], (v2f){h,  h},  p1);
            p0 = pk_fma(whh0[1], (v2f){h1, h1}, p0);
            p1 = pk_fma(whh1[1], (v2f){h1, h1}, p1);
            p0 = pk_fma(whh0[2], (v2f){h2, h2}, p0);
            p1 = pk_fma(whh1[2], (v2f){h2, h2}, p1);
            p0 = pk_fma(whh0[3], (v2f){h3, h3}, p0);
            p1 = pk_fma(whh1[3], (v2f){h3, h3}, p1);
            // p0 = (af', ai')  p1 = (ag', ao')  (pre-scaled for exp2)

            // ---- gate e-terms: 4 exp2 (quarter-rate pipe) ----
            float ef = __builtin_amdgcn_exp2f(p0.x);
            float eg = __builtin_amdgcn_exp2f(p1.x);
            float ei = __builtin_amdgcn_exp2f(p0.y);
            float eo = __builtin_amdgcn_exp2f(p1.y);

            v2f P0 = (v2f){ef, ei} + (v2f){1.0f, 1.0f};  // (pf, pi)
            v2f P1 = (v2f){eg, eo} + (v2f){1.0f, 1.0f};  // (pg, po)

            // ---- merged cell update: one rcp for f, i, g ----
            // qg = MT*(1-eg);  s' = (s*pi*pg + pf*qg) / (pf*pi*pg)
            float qg  = fmaf(2.88539008f, eg, -2.88539008f);
            float pig = P0.y * P1.x;
            float t1  = P0.x * qg;
            float NUM = fmaf(s, pig, t1);
            float DEN = P0.x * pig;
            float rD  = __builtin_amdgcn_rcpf(DEN);
            s = fminf(NUM * rD, 88.0f);   // upper guard; lower side flushes

            // ---- merged output: one rcp for o and tanh(c) ----
            // h = (1 - es) / (po * (1 + es))
            float es = __builtin_amdgcn_exp2f(s);
            float ps = 1.0f + es;
            float NH = 1.0f - es;
            float DH = P1.y * ps;
            float rH = __builtin_amdgcn_rcpf(DH);
            h = NH * rH;
        }
#pragma unroll
        for (int i = 0; i < CH; ++i) cur[i] = nxt[i];
    }

    // out[b] = sum_j h_j * W_fc[j] + b_fc  (reduce across the quad)
    float partial = h * W_fc[j];
    partial += quad_xor<0xB1>(partial);
    partial += quad_xor<0x4E>(partial);
    if (j == 0) out[b] = partial + b_fc[0];
}

extern "C" void kernel_launch(void* const* d_in, const int* in_sizes, int n_in,
                              void* d_out, int out_size, void* d_ws, size_t ws_size,
                              hipStream_t stream) {
    const float* X    = (const float*)d_in[0];
    const float* W_ih = (const float*)d_in[1];
    const float* W_hh = (const float*)d_in[2];
    const float* b_ih = (const float*)d_in[3];
    const float* b_hh = (const float*)d_in[4];
    const float* W_fc = (const float*)d_in[5];
    const float* b_fc = (const float*)d_in[6];
    float* out = (float*)d_out;

    int B = out_size;                       // 16384
    int T = in_sizes[0] / (B * 4);          // 512 (I=4)

    int threads = B * 4;
    dim3 block(256);
    dim3 grid((threads + 255) / 256);
    lstm_h4_kernel<<<grid, block, 0, stream>>>(X, W_ih, W_hh, b_ih, b_hh,
                                               W_fc, b_fc, out, B, T);
}

// Round 4
// 241.471 us; speedup vs baseline: 1.1862x; 1.0216x over previous
//
#include <hip/hip_runtime.h>

// LSTM: B=16384 independent sequences, T=512, I=4, H=4, then FC 4->1.
// Round 6: memory-boundary attack. R5's outcome (removing 3 transcendentals
// saved exactly their ISSUE cost, 511->485 cyc/step) exonerates trans
// latency; R4 exonerated ALU chain latency; R3 exonerated occupancy. The
// ~295 stall cyc/step must come from X-prefetch latency exposed at chunk
// boundaries (8-step in-flight window ~1500 cy < congested HBM latency).
// Fix (compute body identical to R5 -- single-variable experiment):
//   - CH 8 -> 16: half as many chunk boundaries
//   - ping-pong buffers with duplicated body: no cur=nxt copy train, and
//     each buffer's loads stay in flight for a full 16-step opposite-phase
//     compute (~2x latency tolerance)
//   - branchless clamped prefetch (last chunk reloads redundantly)

#define CH 16  // time-chunk for ping-pong X prefetch

typedef float v2f __attribute__((ext_vector_type(2)));

__device__ __forceinline__ v2f pk_fma(v2f a, v2f b, v2f c) {
    return __builtin_elementwise_fma(a, b, c);
}

// DPP quad_perm lane xor within aligned quads: xor1=0xB1, xor2=0x4E, xor3=0x1B
template <int CTRL>
__device__ __forceinline__ float quad_xor(float v) {
    int i = __float_as_int(v);
    int r = __builtin_amdgcn_mov_dpp(i, CTRL, 0xF, 0xF, true);
    return __int_as_float(r);
}

__global__ __launch_bounds__(256) void lstm_h4_kernel(
    const float* __restrict__ X,
    const float* __restrict__ W_ih,
    const float* __restrict__ W_hh,
    const float* __restrict__ b_ih,
    const float* __restrict__ b_hh,
    const float* __restrict__ W_fc,
    const float* __restrict__ b_fc,
    float* __restrict__ out,
    int B, int T)
{
    int gid = blockIdx.x * blockDim.x + threadIdx.x;
    int b = gid >> 2;       // sequence index
    int j = gid & 3;        // hidden unit index
    if (b >= B) return;

    // Gate order (PyTorch rows): 0-3=i, 4-7=f, 8-11=g, 12-15=o.
    // Pair 0 = (f_j, i_j) rows (4+j, j); pair 1 = (g_j, o_j) rows (8+j,12+j).
    // exp2 pre-scales folded: sigmoid rows * MS, tanh (g) row * MT.
    const float MS = -1.44269504f;   // -log2(e)
    const float MT = -2.88539008f;   // -2*log2(e)

    v2f wih0[4], wih1[4], whh0[4], whh1[4], bias0, bias1;
    {
        int rI = 0 * 4 + j, rF = 1 * 4 + j, rG = 2 * 4 + j, rO = 3 * 4 + j;
#pragma unroll
        for (int k = 0; k < 4; ++k) {
            wih0[k] = (v2f){MS * W_ih[rF * 4 + k], MS * W_ih[rI * 4 + k]};
            wih1[k] = (v2f){MT * W_ih[rG * 4 + k], MS * W_ih[rO * 4 + k]};
            int kc = j ^ k;
            whh0[k] = (v2f){MS * W_hh[rF * 4 + kc], MS * W_hh[rI * 4 + kc]};
            whh1[k] = (v2f){MT * W_hh[rG * 4 + kc], MS * W_hh[rO * 4 + kc]};
        }
        bias0 = (v2f){MS * (b_ih[rF] + b_hh[rF]), MS * (b_ih[rI] + b_hh[rI])};
        bias1 = (v2f){MT * (b_ih[rG] + b_hh[rG]), MS * (b_ih[rO] + b_hh[rO])};
    }

    const float4* __restrict__ xp = (const float4*)X + (size_t)b * T;

    float h = 0.0f;
    float s = 0.0f;   // scaled cell state: s = -2.8854 * c

    float4 bufA[CH], bufB[CH];

#define LOADBUF(buf, tbase)                                             \
    {                                                                   \
        int t0_ = (tbase);                                              \
        if (t0_ > T - CH) t0_ = T - CH;                                 \
        _Pragma("unroll")                                               \
        for (int i_ = 0; i_ < CH; ++i_) buf[i_] = xp[t0_ + i_];         \
    }

#define STEP(xv)                                                        \
    {                                                                   \
        float4 x = (xv);                                                \
        v2f p0 = bias0, p1 = bias1;                                     \
        p0 = pk_fma(wih0[0], (v2f){x.x, x.x}, p0);                      \
        p1 = pk_fma(wih1[0], (v2f){x.x, x.x}, p1);                      \
        p0 = pk_fma(wih0[1], (v2f){x.y, x.y}, p0);                      \
        p1 = pk_fma(wih1[1], (v2f){x.y, x.y}, p1);                      \
        p0 = pk_fma(wih0[2], (v2f){x.z, x.z}, p0);                      \
        p1 = pk_fma(wih1[2], (v2f){x.z, x.z}, p1);                      \
        p0 = pk_fma(wih0[3], (v2f){x.w, x.w}, p0);                      \
        p1 = pk_fma(wih1[3], (v2f){x.w, x.w}, p1);                      \
        float h1 = quad_xor<0xB1>(h);                                   \
        float h2 = quad_xor<0x4E>(h);                                   \
        float h3 = quad_xor<0x1B>(h);                                   \
        p0 = pk_fma(whh0[0], (v2f){h,  h},  p0);                        \
        p1 = pk_fma(whh1[0], (v2f){h,  h},  p1);                        \
        p0 = pk_fma(whh0[1], (v2f){h1, h1}, p0);                        \
        p1 = pk_fma(whh1[1], (v2f){h1, h1}, p1);                        \
        p0 = pk_fma(whh0[2], (v2f){h2, h2}, p0);                        \
        p1 = pk_fma(whh1[2], (v2f){h2, h2}, p1);                        \
        p0 = pk_fma(whh0[3], (v2f){h3, h3}, p0);                        \
        p1 = pk_fma(whh1[3], (v2f){h3, h3}, p1);                        \
        float ef = __builtin_amdgcn_exp2f(p0.x);                        \
        float eg = __builtin_amdgcn_exp2f(p1.x);                        \
        float ei = __builtin_amdgcn_exp2f(p0.y);                        \
        float eo = __builtin_amdgcn_exp2f(p1.y);                        \
        v2f P0 = (v2f){ef, ei} + (v2f){1.0f, 1.0f};                     \
        v2f P1 = (v2f){eg, eo} + (v2f){1.0f, 1.0f};                     \
        float qg  = fmaf(2.88539008f, eg, -2.88539008f);                \
        float pig = P0.y * P1.x;                                        \
        float t1  = P0.x * qg;                                          \
        float NUM = fmaf(s, pig, t1);                                   \
        float DEN = P0.x * pig;                                         \
        float rD  = __builtin_amdgcn_rcpf(DEN);                         \
        s = fminf(NUM * rD, 88.0f);                                     \
        float es = __builtin_amdgcn_exp2f(s);                           \
        float ps = 1.0f + es;                                           \
        float NH = 1.0f - es;                                           \
        float DH = P1.y * ps;                                           \
        float rH = __builtin_amdgcn_rcpf(DH);                           \
        h = NH * rH;                                                    \
    }

    LOADBUF(bufA, 0);

    for (int tc = 0; tc < T; tc += 2 * CH) {
        LOADBUF(bufB, tc + CH);
#pragma unroll
        for (int i = 0; i < CH; ++i) STEP(bufA[i]);
        LOADBUF(bufA, tc + 2 * CH);
#pragma unroll
        for (int i = 0; i < CH; ++i) STEP(bufB[i]);
    }

    // out[b] = sum_j h_j * W_fc[j] + b_fc  (reduce across the quad)
    float partial = h * W_fc[j];
    partial += quad_xor<0xB1>(partial);
    partial += quad_xor<0x4E>(partial);
    if (j == 0) out[b] = partial + b_fc[0];
}

extern "C" void kernel_launch(void* const* d_in, const int* in_sizes, int n_in,
                              void* d_out, int out_size, void* d_ws, size_t ws_size,
                              hipStream_t stream) {
    const float* X    = (const float*)d_in[0];
    const float* W_ih = (const float*)d_in[1];
    const float* W_hh = (const float*)d_in[2];
    const float* b_ih = (const float*)d_in[3];
    const float* b_hh = (const float*)d_in[4];
    const float* W_fc = (const float*)d_in[5];
    const float* b_fc = (const float*)d_in[6];
    float* out = (float*)d_out;

    int B = out_size;                       // 16384
    int T = in_sizes[0] / (B * 4);          // 512 (I=4)

    int threads = B * 4;
    dim3 block(256);
    dim3 grid((threads + 255) / 256);
    lstm_h4_kernel<<<grid, block, 0, stream>>>(X, W_ih, W_hh, b_ih, b_hh,
                                               W_fc, b_fc, out, B, T);
}